// Round 7
// baseline (275.449 us; speedup 1.0000x reference)
//
#include <hip/hip_runtime.h>

// Problem constants (from reference setup_inputs)
#define F_FACES 6144
#define VN      5000

// sqrt(625 * log2(e))  -- C pre-scale: exp2 arg = ai + aj + 2*dot(C'i,C'j)
#define SC_F    30.02806022f
// sqrt(4 * log2(e))    -- N pre-scale: ndot term = dot(N'i,N'j)
#define SN_F    2.40224481f
// 4 * log2(e)
#define C4_F    5.7707801635558535f

// Raw v_exp_f32 — ~16 cyc/wave64 measured; 2 per pair = half the issue demand.
__device__ __forceinline__ float fast_exp2(float x) {
    float r; asm("v_exp_f32 %0, %1" : "=v"(r) : "v"(x)); return r;
}

// ws layout: [0, 786432)  mesh float4 pairs (4 meshes x 6144 faces x 2)
//            [786432, +4096)  64 accumulator cells, stride 16 floats
//            [790528, +4)     completion counter (int)
#define CELLS_OFF_FLOATS (4 * F_FACES * 2 * 4)   // 196608 floats
#define COUNTER_OFF_INTS (CELLS_OFF_FLOATS + 64 * 16)

// ---------------------------------------------------------------------------
// Kernel 1: per-face quantities for 4 meshes; zeroes cells + counter.
//   A = [Cx*SC, Cy*SC, Cz*SC, -|C*SC|^2]
//   B = [Nx*inv*SN, Ny*inv*SN, Nz*inv*SN, log2(L) - 4*log2e]
// B.w folds Lj and the -4*log2e constant into the normal-kernel exp2.
// ---------------------------------------------------------------------------
__global__ __launch_bounds__(256) void mesh_prep(
    const float* __restrict__ pred, const float* __restrict__ targ,
    const int* __restrict__ faces, float4* __restrict__ ws4,
    float* __restrict__ cells, int* __restrict__ counter)
{
    const int f = blockIdx.x * 256 + threadIdx.x;
    const int m = blockIdx.y;                    // mesh id = b*2 + which
    if (blockIdx.x == 0 && m == 0) {
        if (threadIdx.x < 64) cells[threadIdx.x * 16] = 0.0f;
        if (threadIdx.x == 64) counter[0] = 0;
    }
    if (f >= F_FACES) return;

    const int b = m >> 1, which = m & 1;
    const float* V = (which ? targ : pred) + b * (VN * 3);

    const int i0 = faces[3 * f + 0];
    const int i1 = faces[3 * f + 1];
    const int i2 = faces[3 * f + 2];

    const float v0x = V[3 * i0 + 0], v0y = V[3 * i0 + 1], v0z = V[3 * i0 + 2];
    const float v1x = V[3 * i1 + 0], v1y = V[3 * i1 + 1], v1z = V[3 * i1 + 2];
    const float v2x = V[3 * i2 + 0], v2y = V[3 * i2 + 1], v2z = V[3 * i2 + 2];

    const float Cx = (v0x + v1x + v2x) * (1.0f / 3.0f);
    const float Cy = (v0y + v1y + v2y) * (1.0f / 3.0f);
    const float Cz = (v0z + v1z + v2z) * (1.0f / 3.0f);

    const float e1x = v1x - v0x, e1y = v1y - v0y, e1z = v1z - v0z;
    const float e2x = v2x - v0x, e2y = v2y - v0y, e2z = v2z - v0z;

    const float Nx = 0.5f * (e1y * e2z - e1z * e2y);
    const float Ny = 0.5f * (e1z * e2x - e1x * e2z);
    const float Nz = 0.5f * (e1x * e2y - e1y * e2x);

    const float l2  = Nx * Nx + Ny * Ny + Nz * Nz + 1e-24f;
    const float L   = sqrtf(l2);
    const float inv = 1.0f / L;

    const float Csx = Cx * SC_F, Csy = Cy * SC_F, Csz = Cz * SC_F;
    const float a   = -(Csx * Csx + Csy * Csy + Csz * Csz);
    const float s   = inv * SN_F;

    const long base = (long)(m * F_FACES + f) * 2;
    ws4[base + 0] = make_float4(Csx, Csy, Csz, a);
    ws4[base + 1] = make_float4(Nx * s, Ny * s, Nz * s, log2f(L) - C4_F);
}

// ---------------------------------------------------------------------------
// Kernel 2: pair sums over flattened, balanced column space + in-kernel
// completion: last block reduces the 64 cells and writes out[0].
// Column = (band, j-face); band = 512-row i-band of one (c,b,it).
//   tri bands (ss,tt): j in [512*it, 6144); st bands: j in [0, 6144)
// Total columns = 4*39936 + 24*6144 = 307200 = 12288 blocks x 25.
// 12288 divisible by 2048/3072/4096 -> exact occupancy rounds, no ragged tail.
// Per pair: 16 VALU (2cyc) + 2 v_exp_f32 (~16cyc) = 64 cyc/wave-iter serial.
// ---------------------------------------------------------------------------
#define BLK       128
#define IT        4
#define I_ROWS    (BLK * IT)              // 512
#define I_TILES   (F_FACES / I_ROWS)      // 12
#define W_TRI_Q   39936                   // per (c,b) triangle columns
#define TRI_TOTAL (4 * W_TRI_Q)           // 159744
#define N_BLOCKS  12288
#define CPB       25                      // columns per block

__global__ __launch_bounds__(BLK, 8) void varifold_pairs(
    const float4* __restrict__ ws4, float* __restrict__ cells,
    int* __restrict__ counter, float* __restrict__ out)
{
    __shared__ float4 sAB[2 * CPB];
    __shared__ float  red[2];
    __shared__ int    lastFlag;

    const int tid = threadIdx.x;
    int col = blockIdx.x * CPB;
    int remaining = CPB;
    float total = 0.0f;

    int cur_key = -1;   // (m1*16 + it) of cached i-state
    float C2x[IT], C2y[IT], C2z[IT], Ai[IT];
    float Nix[IT], Niy[IT], Niz[IT], Li[IT];
    float acc[IT];

    while (remaining > 0) {
        // ---- decode col -> (c, b, it, j, r, bandLeft) ----
        int c, b, it, j, r, bandLeft;
        if (col < TRI_TOTAL) {
            const int q = col / W_TRI_Q;         // 0..3
            r = col - q * W_TRI_Q;
            c = (q >> 1) ? 2 : 0; b = q & 1;
            it = 0;
            int w = F_FACES;
            while (r >= w) { r -= w; ++it; w -= I_ROWS; }
            j = it * I_ROWS + r;
            bandLeft = w - r;
        } else {
            const int lin = col - TRI_TOTAL;
            const int band = lin / F_FACES;
            r = lin - band * F_FACES;
            j = r;
            b = band / I_TILES; it = band - (band / I_TILES) * I_TILES;
            c = 1;
            bandLeft = F_FACES - r;
        }
        const bool strad = (c != 1) && (r < I_ROWS);
        int segLen = min(remaining, bandLeft);
        if (strad) segLen = min(segLen, I_ROWS - r);
        const float wOut = (c == 1) ? -1.0f : (strad ? 0.5f : 1.0f);
        const int m1 = 2 * b + (c == 2 ? 1 : 0);
        const int m2 = 2 * b + (c >= 1 ? 1 : 0);
        const float4* P1 = ws4 + (long)m1 * (F_FACES * 2);
        const float4* P2 = ws4 + (long)m2 * (F_FACES * 2);
        const int iBase = it * I_ROWS;

        // ---- (re)load i-state if band changed ----
        const int key = m1 * 16 + it;
        if (key != cur_key) {
            cur_key = key;
#pragma unroll
            for (int k = 0; k < IT; ++k) {
                const int i = iBase + k * BLK + tid;
                const float4 A  = P1[2 * i + 0];
                const float4 Bv = P1[2 * i + 1];
                C2x[k] = 2.0f * A.x; C2y[k] = 2.0f * A.y; C2z[k] = 2.0f * A.z;
                Ai[k]  = A.w;
                Nix[k] = Bv.x; Niy[k] = Bv.y; Niz[k] = Bv.z;
                Li[k]  = fast_exp2(Bv.w + C4_F);
            }
        }
#pragma unroll
        for (int k = 0; k < IT; ++k) acc[k] = 0.0f;

        // ---- stage segment's j-faces (coalesced float4 from ws4) ----
        __syncthreads();   // previous segment done reading sAB
        if (tid < 2 * segLen) sAB[tid] = P2[2 * j + tid];
        __syncthreads();

        if (!strad) {
            for (int jj = 0; jj < segLen; ++jj) {
                const float4 a4 = sAB[2 * jj + 0];
                const float4 b4 = sAB[2 * jj + 1];
#pragma unroll
                for (int k = 0; k < IT; ++k) {
                    float rr = fmaf(C2x[k], a4.x, a4.w);
                    rr = fmaf(C2y[k], a4.y, rr);
                    rr = fmaf(C2z[k], a4.z, rr);
                    const float t0 = fast_exp2(rr + Ai[k]);  // exp(-625 d2)
                    float n = fmaf(Nix[k], b4.x, b4.w);
                    n = fmaf(Niy[k], b4.y, n);
                    n = fmaf(Niz[k], b4.z, n);
                    const float en = fast_exp2(n);           // Lj*exp(4(nd-1))
                    const float t2  = t0 * t0;
                    const float t4  = t2 * t2;
                    const float t8  = t4 * t4;
                    const float t16 = t8 * t8;
                    const float t24 = t16 * t8;
                    const float t25 = t24 * t0;
                    float p = fmaf(0.25f, t16, t4);
                    p = fmaf(0.16f, t25, p);
                    acc[k] = fmaf(en, p, acc[k]);
                }
            }
        } else {
            for (int jj = 0; jj < segLen; ++jj) {
                const float4 a4 = sAB[2 * jj + 0];
                const float4 b4 = sAB[2 * jj + 1];
                const int jg = j + jj;
#pragma unroll
                for (int k = 0; k < IT; ++k) {
                    const int i = iBase + k * BLK + tid;
                    float rr = fmaf(C2x[k], a4.x, a4.w);
                    rr = fmaf(C2y[k], a4.y, rr);
                    rr = fmaf(C2z[k], a4.z, rr);
                    const float t0 = fast_exp2(rr + Ai[k]);
                    float n = fmaf(Nix[k], b4.x, b4.w);
                    n = fmaf(Niy[k], b4.y, n);
                    n = fmaf(Niz[k], b4.z, n);
                    const float en = fast_exp2(n);
                    const float t2  = t0 * t0;
                    const float t4  = t2 * t2;
                    const float t8  = t4 * t4;
                    const float t16 = t8 * t8;
                    const float t24 = t16 * t8;
                    const float t25 = t24 * t0;
                    float p = fmaf(0.25f, t16, t4);
                    p = fmaf(0.16f, t25, p);
                    float fw = (jg > i) ? 2.0f : 0.0f;       // upper x2
                    fw = (jg == i) ? 1.0f : fw;              // diagonal x1
                    acc[k] = fmaf(fw * en, p, acc[k]);
                }
            }
        }

        // fold segment into thread total with segment weight
        float part = 0.0f;
#pragma unroll
        for (int k = 0; k < IT; ++k) part = fmaf(acc[k], Li[k], part);
        total = fmaf(wOut, part, total);

        col += segLen; remaining -= segLen;
    }

    // ---- block reduce (2 waves) ----
#pragma unroll
    for (int off = 32; off; off >>= 1) total += __shfl_xor(total, off);
    if ((tid & 63) == 0) red[tid >> 6] = total;
    __syncthreads();

    // ---- spread atomic + completion detection (device-scope) ----
    if (tid == 0) {
        atomicAdd(&cells[(blockIdx.x & 63) * 16], red[0] + red[1]);
        __threadfence();                      // cell add visible before count
        const int old = atomicAdd(counter, 1);
        lastFlag = (old == N_BLOCKS - 1);
    }
    __syncthreads();

    // ---- last block: sum the 64 cells (coherent atomic reads) -> out ----
    if (lastFlag && tid < 64) {
        __threadfence();
        float v = atomicAdd(&cells[tid * 16], 0.0f);   // device-coherent read
#pragma unroll
        for (int off = 32; off; off >>= 1) v += __shfl_xor(v, off);
        if (tid == 0) out[0] = v;
    }
}

// ---------------------------------------------------------------------------
extern "C" void kernel_launch(void* const* d_in, const int* in_sizes, int n_in,
                              void* d_out, int out_size, void* d_ws, size_t ws_size,
                              hipStream_t stream) {
    const float* pred  = (const float*)d_in[0];
    const float* targ  = (const float*)d_in[1];
    const int*   faces = (const int*)d_in[2];
    float*       out   = (float*)d_out;
    float4*      ws4   = (float4*)d_ws;                        // 786432 B
    float*       cells = (float*)d_ws + CELLS_OFF_FLOATS;      // 64 x 64B
    int*         counter = (int*)d_ws + COUNTER_OFF_INTS;      // 1 int

    dim3 g1(F_FACES / 256, 4);
    mesh_prep<<<g1, 256, 0, stream>>>(pred, targ, faces, ws4, cells, counter);

    varifold_pairs<<<dim3(N_BLOCKS), dim3(BLK), 0, stream>>>(ws4, cells, counter, out);
}

// Round 8
// 134.813 us; speedup vs baseline: 2.0432x; 2.0432x over previous
//
#include <hip/hip_runtime.h>

// Problem constants (from reference setup_inputs)
#define F_FACES 6144
#define VN      5000

// sqrt(625 * log2(e))  -- C pre-scale: exp2 arg = ai + aj + 2*dot(C'i,C'j)
#define SC_F    30.02806022f
// sqrt(4 * log2(e))    -- N pre-scale: ndot term = dot(N'i,N'j)
#define SN_F    2.40224481f
// 4 * log2(e)
#define C4_F    5.7707801635558535f

// Raw v_exp_f32 — ~16 cyc/wave64 measured; 2 per pair = half the issue demand.
__device__ __forceinline__ float fast_exp2(float x) {
    float r; asm("v_exp_f32 %0, %1" : "=v"(r) : "v"(x)); return r;
}

// ws layout: [0, 786432)  mesh float4 pairs (4 meshes x 6144 faces x 2)
//            [786432, +4096)  64 accumulator cells, stride 16 floats (64 B)
#define CELLS_OFF_FLOATS (4 * F_FACES * 2 * 4)   // 196608 floats

// ---------------------------------------------------------------------------
// Kernel 1: per-face quantities for 4 meshes; zeroes the 64 partial cells.
//   A = [Cx*SC, Cy*SC, Cz*SC, -|C*SC|^2]
//   B = [Nx*inv*SN, Ny*inv*SN, Nz*inv*SN, log2(L) - 4*log2e]
// B.w folds Lj and the -4*log2e constant into the normal-kernel exp2.
// ---------------------------------------------------------------------------
__global__ __launch_bounds__(256) void mesh_prep(
    const float* __restrict__ pred, const float* __restrict__ targ,
    const int* __restrict__ faces, float4* __restrict__ ws4,
    float* __restrict__ cells)
{
    const int f = blockIdx.x * 256 + threadIdx.x;
    const int m = blockIdx.y;                    // mesh id = b*2 + which
    if (blockIdx.x == 0 && m == 0 && threadIdx.x < 64)
        cells[threadIdx.x * 16] = 0.0f;
    if (f >= F_FACES) return;

    const int b = m >> 1, which = m & 1;
    const float* V = (which ? targ : pred) + b * (VN * 3);

    const int i0 = faces[3 * f + 0];
    const int i1 = faces[3 * f + 1];
    const int i2 = faces[3 * f + 2];

    const float v0x = V[3 * i0 + 0], v0y = V[3 * i0 + 1], v0z = V[3 * i0 + 2];
    const float v1x = V[3 * i1 + 0], v1y = V[3 * i1 + 1], v1z = V[3 * i1 + 2];
    const float v2x = V[3 * i2 + 0], v2y = V[3 * i2 + 1], v2z = V[3 * i2 + 2];

    const float Cx = (v0x + v1x + v2x) * (1.0f / 3.0f);
    const float Cy = (v0y + v1y + v2y) * (1.0f / 3.0f);
    const float Cz = (v0z + v1z + v2z) * (1.0f / 3.0f);

    const float e1x = v1x - v0x, e1y = v1y - v0y, e1z = v1z - v0z;
    const float e2x = v2x - v0x, e2y = v2y - v0y, e2z = v2z - v0z;

    const float Nx = 0.5f * (e1y * e2z - e1z * e2y);
    const float Ny = 0.5f * (e1z * e2x - e1x * e2z);
    const float Nz = 0.5f * (e1x * e2y - e1y * e2x);

    const float l2  = Nx * Nx + Ny * Ny + Nz * Nz + 1e-24f;
    const float L   = sqrtf(l2);
    const float inv = 1.0f / L;

    const float Csx = Cx * SC_F, Csy = Cy * SC_F, Csz = Cz * SC_F;
    const float a   = -(Csx * Csx + Csy * Csy + Csz * Csz);
    const float s   = inv * SN_F;

    const long base = (long)(m * F_FACES + f) * 2;
    ws4[base + 0] = make_float4(Csx, Csy, Csz, a);
    ws4[base + 1] = make_float4(Nx * s, Ny * s, Nz * s, log2f(L) - C4_F);
}

// ---------------------------------------------------------------------------
// Kernel 2: pair sums over flattened, balanced column space.
// Column = (band, j-face); band = 512-row i-band of one (c,b,it).
//   tri bands (ss,tt): j in [512*it, 6144); st bands: j in [0, 6144)
// Total columns = 4*39936 + 24*6144 = 307200 = 4096 blocks x 75.
// 4096 blocks = 16 blocks/CU = the 32-waves/CU residency cap (2-wave blocks,
// VGPR 32, LDS 2.4KB) -> ONE fully-resident round, no inter-round ramp, and
// the per-block i-state prologue amortizes over 75 columns (~3%).
// Per pair: 16 VALU (2cyc) + 2 v_exp_f32 (~16cyc) = 64 cyc/wave-iter serial.
// ---------------------------------------------------------------------------
#define BLK       128
#define IT        4
#define I_ROWS    (BLK * IT)              // 512
#define I_TILES   (F_FACES / I_ROWS)      // 12
#define W_TRI_Q   39936                   // per (c,b) triangle columns
#define TRI_TOTAL (4 * W_TRI_Q)           // 159744
#define N_BLOCKS  4096
#define CPB       75                      // columns per block

__global__ __launch_bounds__(BLK, 8) void varifold_pairs(
    const float4* __restrict__ ws4, float* __restrict__ cells)
{
    __shared__ float4 sAB[2 * CPB];
    __shared__ float  red[2];

    const int tid = threadIdx.x;
    int col = blockIdx.x * CPB;
    int remaining = CPB;
    float total = 0.0f;

    int cur_key = -1;   // (m1*16 + it) of cached i-state
    float C2x[IT], C2y[IT], C2z[IT], Ai[IT];
    float Nix[IT], Niy[IT], Niz[IT], Li[IT];
    float acc[IT];

    while (remaining > 0) {
        // ---- decode col -> (c, b, it, j, r, bandLeft) ----
        int c, b, it, j, r, bandLeft;
        if (col < TRI_TOTAL) {
            const int q = col / W_TRI_Q;         // 0..3
            r = col - q * W_TRI_Q;
            c = (q >> 1) ? 2 : 0; b = q & 1;
            it = 0;
            int w = F_FACES;
            while (r >= w) { r -= w; ++it; w -= I_ROWS; }
            j = it * I_ROWS + r;
            bandLeft = w - r;
        } else {
            const int lin = col - TRI_TOTAL;
            const int band = lin / F_FACES;
            r = lin - band * F_FACES;
            j = r;
            b = band / I_TILES; it = band - (band / I_TILES) * I_TILES;
            c = 1;
            bandLeft = F_FACES - r;
        }
        const bool strad = (c != 1) && (r < I_ROWS);
        int segLen = min(remaining, bandLeft);
        if (strad) segLen = min(segLen, I_ROWS - r);
        const float wOut = (c == 1) ? -1.0f : (strad ? 0.5f : 1.0f);
        const int m1 = 2 * b + (c == 2 ? 1 : 0);
        const int m2 = 2 * b + (c >= 1 ? 1 : 0);
        const float4* P1 = ws4 + (long)m1 * (F_FACES * 2);
        const float4* P2 = ws4 + (long)m2 * (F_FACES * 2);
        const int iBase = it * I_ROWS;

        // ---- (re)load i-state if band changed ----
        const int key = m1 * 16 + it;
        if (key != cur_key) {
            cur_key = key;
#pragma unroll
            for (int k = 0; k < IT; ++k) {
                const int i = iBase + k * BLK + tid;
                const float4 A  = P1[2 * i + 0];
                const float4 Bv = P1[2 * i + 1];
                C2x[k] = 2.0f * A.x; C2y[k] = 2.0f * A.y; C2z[k] = 2.0f * A.z;
                Ai[k]  = A.w;
                Nix[k] = Bv.x; Niy[k] = Bv.y; Niz[k] = Bv.z;
                Li[k]  = fast_exp2(Bv.w + C4_F);
            }
        }
#pragma unroll
        for (int k = 0; k < IT; ++k) acc[k] = 0.0f;

        // ---- stage segment's j-faces (2*segLen float4, strided loop) ----
        __syncthreads();   // previous segment done reading sAB
        for (int s = tid; s < 2 * segLen; s += BLK) sAB[s] = P2[2 * j + s];
        __syncthreads();

        if (!strad) {
            for (int jj = 0; jj < segLen; ++jj) {
                const float4 a4 = sAB[2 * jj + 0];
                const float4 b4 = sAB[2 * jj + 1];
#pragma unroll
                for (int k = 0; k < IT; ++k) {
                    float rr = fmaf(C2x[k], a4.x, a4.w);
                    rr = fmaf(C2y[k], a4.y, rr);
                    rr = fmaf(C2z[k], a4.z, rr);
                    const float t0 = fast_exp2(rr + Ai[k]);  // exp(-625 d2)
                    float n = fmaf(Nix[k], b4.x, b4.w);
                    n = fmaf(Niy[k], b4.y, n);
                    n = fmaf(Niz[k], b4.z, n);
                    const float en = fast_exp2(n);           // Lj*exp(4(nd-1))
                    const float t2  = t0 * t0;
                    const float t4  = t2 * t2;
                    const float t8  = t4 * t4;
                    const float t16 = t8 * t8;
                    const float t24 = t16 * t8;
                    const float t25 = t24 * t0;
                    float p = fmaf(0.25f, t16, t4);
                    p = fmaf(0.16f, t25, p);
                    acc[k] = fmaf(en, p, acc[k]);
                }
            }
        } else {
            for (int jj = 0; jj < segLen; ++jj) {
                const float4 a4 = sAB[2 * jj + 0];
                const float4 b4 = sAB[2 * jj + 1];
                const int jg = j + jj;
#pragma unroll
                for (int k = 0; k < IT; ++k) {
                    const int i = iBase + k * BLK + tid;
                    float rr = fmaf(C2x[k], a4.x, a4.w);
                    rr = fmaf(C2y[k], a4.y, rr);
                    rr = fmaf(C2z[k], a4.z, rr);
                    const float t0 = fast_exp2(rr + Ai[k]);
                    float n = fmaf(Nix[k], b4.x, b4.w);
                    n = fmaf(Niy[k], b4.y, n);
                    n = fmaf(Niz[k], b4.z, n);
                    const float en = fast_exp2(n);
                    const float t2  = t0 * t0;
                    const float t4  = t2 * t2;
                    const float t8  = t4 * t4;
                    const float t16 = t8 * t8;
                    const float t24 = t16 * t8;
                    const float t25 = t24 * t0;
                    float p = fmaf(0.25f, t16, t4);
                    p = fmaf(0.16f, t25, p);
                    float fw = (jg > i) ? 2.0f : 0.0f;       // upper x2
                    fw = (jg == i) ? 1.0f : fw;              // diagonal x1
                    acc[k] = fmaf(fw * en, p, acc[k]);
                }
            }
        }

        // fold segment into thread total with segment weight
        float part = 0.0f;
#pragma unroll
        for (int k = 0; k < IT; ++k) part = fmaf(acc[k], Li[k], part);
        total = fmaf(wOut, part, total);

        col += segLen; remaining -= segLen;
    }

    // block reduce (2 waves), one spread atomic per block (64 cells)
#pragma unroll
    for (int off = 32; off; off >>= 1) total += __shfl_xor(total, off);
    if ((tid & 63) == 0) red[tid >> 6] = total;
    __syncthreads();
    if (tid == 0)
        atomicAdd(&cells[(blockIdx.x & 63) * 16], red[0] + red[1]);
}

// ---------------------------------------------------------------------------
// Kernel 3: sum the 64 cells -> out[0].
// ---------------------------------------------------------------------------
__global__ __launch_bounds__(64) void finalize_sum(
    const float* __restrict__ cells, float* __restrict__ out)
{
    float v = cells[threadIdx.x * 16];
#pragma unroll
    for (int off = 32; off; off >>= 1) v += __shfl_xor(v, off);
    if (threadIdx.x == 0) out[0] = v;
}

// ---------------------------------------------------------------------------
extern "C" void kernel_launch(void* const* d_in, const int* in_sizes, int n_in,
                              void* d_out, int out_size, void* d_ws, size_t ws_size,
                              hipStream_t stream) {
    const float* pred  = (const float*)d_in[0];
    const float* targ  = (const float*)d_in[1];
    const int*   faces = (const int*)d_in[2];
    float*       out   = (float*)d_out;
    float4*      ws4   = (float4*)d_ws;                       // 786432 B
    float*       cells = (float*)d_ws + CELLS_OFF_FLOATS;     // 64 x 64B

    dim3 g1(F_FACES / 256, 4);
    mesh_prep<<<g1, 256, 0, stream>>>(pred, targ, faces, ws4, cells);

    varifold_pairs<<<dim3(N_BLOCKS), dim3(BLK), 0, stream>>>(ws4, cells);

    finalize_sum<<<dim3(1), dim3(64), 0, stream>>>(cells, out);
}